// Round 19
// baseline (4492.649 us; speedup 1.0000x reference)
//
#include <hip/hip_runtime.h>
#include <hip/hip_bf16.h>

#define B_ 1024
#define T_ 128
#define E_ 128
#define U_ 512
#define V_ 32000
#define NC 16   // col chunks
#define NG 16   // row groups
#define MB 64   // rows per group
#define NB 32   // cols per chunk
#define HS ((size_t)B_ * U_)

// ws layout
#define H0H_OFF (0u << 20)   // 2 buffers x 1 MB
#define H0L_OFF (2u << 20)
#define H1H_OFF (4u << 20)
#define H1L_OFF (6u << 20)
#define WT_OFF (8u << 20)    // 5 x 512 KB transposed bf16 weights
#define EMBW_OFF (11u << 20) // 32.8 MB
#define ZERO_BYTES (8u << 20)

#define WSZ ((size_t)U_ * U_)  // one transposed weight array (elems)

typedef unsigned int uint32;
typedef __bf16 bf16x8 __attribute__((ext_vector_type(8)));
typedef float f32x4 __attribute__((ext_vector_type(4)));
typedef unsigned short us8 __attribute__((ext_vector_type(8)));

#define MFMA __builtin_amdgcn_mfma_f32_16x16x32_bf16

__device__ __forceinline__ unsigned short f2b(float f) {
  uint32 u = __builtin_bit_cast(uint32, f);
  u += 0x7fffu + ((u >> 16) & 1u);   // RNE
  return (unsigned short)(u >> 16);
}
__device__ __forceinline__ float b2f(unsigned short h) {
  return __builtin_bit_cast(float, (uint32)h << 16);
}
__device__ __forceinline__ bf16x8 g_frag(const unsigned short* p) {
  us8 v = *(const us8*)p;
  return __builtin_bit_cast(bf16x8, v);
}

__global__ void rnn_init(unsigned char* ws) {
  const uint4 z = {0u, 0u, 0u, 0u};
  uint4* p = (uint4*)ws;
  size_t n = ZERO_BYTES / 16;
  for (size_t j = (size_t)blockIdx.x * blockDim.x + threadIdx.x; j < n;
       j += (size_t)gridDim.x * blockDim.x)
    p[j] = z;
}

// One-time: transpose + hi/lo-split weights into ws as bf16 [col][k] arrays.
// Values identical to the old LDS staging -> bit-identical MFMA inputs.
__global__ __launch_bounds__(256) void wt_prep(const float* __restrict__ Wh0,
                                               const float* __restrict__ Wx1,
                                               const float* __restrict__ Wh1,
                                               unsigned char* ws) {
  unsigned short* Wh0hT = (unsigned short*)(ws + WT_OFF);
  unsigned short* Wh0lT = Wh0hT + WSZ;
  unsigned short* Wx1hT = Wh0hT + 2 * WSZ;
  unsigned short* Wh1hT = Wh0hT + 3 * WSZ;
  unsigned short* Wh1lT = Wh0hT + 4 * WSZ;
  size_t idx = (size_t)blockIdx.x * blockDim.x + threadIdx.x;
  if (idx >= WSZ) return;
  int k = (int)(idx & (U_ - 1));
  int col = (int)(idx >> 9);
  size_t src = (size_t)k * U_ + col;
  size_t dst = (size_t)col * U_ + k;
  {
    float v = Wh0[src];
    unsigned short hi = f2b(v);
    Wh0hT[dst] = hi;
    Wh0lT[dst] = f2b(v - b2f(hi));
  }
  Wx1hT[dst] = f2b(Wx1[src]);
  {
    float v = Wh1[src];
    unsigned short hi = f2b(v);
    Wh1hT[dst] = hi;
    Wh1lT[dst] = f2b(v - b2f(hi));
  }
}

// embW[v][u] = sum_e emb[v][e] * Wx0[e][u], stored bf16. grid (V/64, U/64).
__global__ __launch_bounds__(256) void embw_gemm(const float* __restrict__ emb,
                                                 const float* __restrict__ Wx0,
                                                 unsigned short* __restrict__ embW) {
  const int tid = threadIdx.x;
  const int lane = tid & 63;
  const int wv = tid >> 6;
  const int arow = lane & 15;
  const int kgrp = (lane >> 4) * 8;
  const int vrow = blockIdx.x * 64 + wv * 16;

  bf16x8 a[4];
  for (int kt = 0; kt < 4; ++kt) {
    const float* p = emb + (size_t)(vrow + arow) * E_ + kt * 32 + kgrp;
    float4 f0 = ((const float4*)p)[0];
    float4 f1 = ((const float4*)p)[1];
    us8 u;
    u[0] = f2b(f0.x); u[1] = f2b(f0.y); u[2] = f2b(f0.z); u[3] = f2b(f0.w);
    u[4] = f2b(f1.x); u[5] = f2b(f1.y); u[6] = f2b(f1.z); u[7] = f2b(f1.w);
    a[kt] = __builtin_bit_cast(bf16x8, u);
  }
  const int c0 = blockIdx.y * 64;
  for (int nt = 0; nt < 4; ++nt) {
    const int col = c0 + nt * 16 + (lane & 15);
    f32x4 acc = {0.f, 0.f, 0.f, 0.f};
    for (int kt = 0; kt < 4; ++kt) {
      us8 ub;
      for (int j = 0; j < 8; ++j)
        ub[j] = f2b(Wx0[(size_t)(kt * 32 + kgrp + j) * U_ + col]);
      acc = MFMA(a[kt], __builtin_bit_cast(bf16x8, ub), acc, 0, 0, 0);
    }
    const int crow = vrow + (lane >> 4) * 4;
    for (int i = 0; i < 4; ++i)
      embW[(size_t)(crow + i) * U_ + col] = f2b(acc[i]);
  }
}

// One merged window (r7 structure): h1'(t-1) lagged + h0'(t). NO intra-kernel
// sync; the kernel boundary IS the group barrier (HW dispatch release/acquire).
__global__ __launch_bounds__(512) void rnn_step(
    int t, const int* __restrict__ tokens, const float* __restrict__ b0,
    const float* __restrict__ b1, unsigned char* ws) {
  const int bid = blockIdx.x;
  // XCD-aware swizzle (perf-only): colocate same-col-chunk blocks per XCD so
  // each XCD's L2 pulls ~2 weight slices instead of 16 per dispatch.
  const int xslot = bid & 7;
  const int j = bid >> 3;
  const int c = xslot * 2 + (j & 1);   // 0..15
  const int g = j >> 1;                // 0..15
  const int r0 = g * MB;
  const int c0 = c * NB;

  unsigned short* h0h = (unsigned short*)(ws + H0H_OFF);
  unsigned short* h0l = (unsigned short*)(ws + H0L_OFF);
  unsigned short* h1h = (unsigned short*)(ws + H1H_OFF);
  unsigned short* h1l = (unsigned short*)(ws + H1L_OFF);
  const unsigned short* Wh0hT = (const unsigned short*)(ws + WT_OFF);
  const unsigned short* Wh0lT = Wh0hT + WSZ;
  const unsigned short* Wx1hT = Wh0hT + 2 * WSZ;
  const unsigned short* Wh1hT = Wh0hT + 3 * WSZ;
  const unsigned short* Wh1lT = Wh0hT + 4 * WSZ;
  const unsigned short* embW = (const unsigned short*)(ws + EMBW_OFF);

  const int tid = threadIdx.x;
  const int lane = tid & 63;
  const int wv = tid >> 6;
  const int mt = wv >> 1;
  const int nt = wv & 1;
  const int l15 = lane & 15;
  const int colL = nt * 16 + l15;
  const int colG = c0 + colL;
  const int rowB = mt * 16 + ((lane >> 4) << 2);
  const int kgrp = (lane >> 4) * 8;
  const int rowA = r0 + mt * 16 + l15;

  const size_t rb0 = (size_t)((t & 1) ^ 1) * HS;  // h0'(t-1)

  // ---- h0'(t-1) fragments (reused by Wx1 and Wh0 chains) ----
  bf16x8 h0h_r[16], h0l_r[16];
  {
    const unsigned short* aph = h0h + rb0 + (size_t)rowA * U_ + kgrp;
    const unsigned short* apl = h0l + rb0 + (size_t)rowA * U_ + kgrp;
#pragma unroll
    for (int kt = 0; kt < 16; ++kt) {
      h0h_r[kt] = g_frag(aph + kt * 32);
      h0l_r[kt] = g_frag(apl + kt * 32);
    }
  }

  // ---- h1'(t-1) = tanh(h0'(t-1)@Wx1 + h1'(t-2)@Wh1 + b1) ----
  if (t >= 1) {
    const float b1v = b1[colG];
    const size_t rb1 = (size_t)(t & 1) * HS;        // h1'(t-2)
    const size_t wb1 = (size_t)((t - 1) & 1) * HS;  // h1'(t-1)
    f32x4 acc = {b1v, b1v, b1v, b1v};
    const unsigned short* a1h = h1h + rb1 + (size_t)rowA * U_ + kgrp;
    const unsigned short* a1l = h1l + rb1 + (size_t)rowA * U_ + kgrp;
    const unsigned short* wx = Wx1hT + (size_t)colG * U_ + kgrp;
    const unsigned short* wh = Wh1hT + (size_t)colG * U_ + kgrp;
    const unsigned short* wl = Wh1lT + (size_t)colG * U_ + kgrp;
#pragma unroll
    for (int kt = 0; kt < 16; ++kt) {
      bf16x8 ah = g_frag(a1h + kt * 32);
      bf16x8 bxh = g_frag(wx + kt * 32);
      bf16x8 bh = g_frag(wh + kt * 32);
      acc = MFMA(h0h_r[kt], bxh, acc, 0, 0, 0);
      acc = MFMA(h0l_r[kt], bxh, acc, 0, 0, 0);
      bf16x8 al = g_frag(a1l + kt * 32);
      acc = MFMA(ah, bh, acc, 0, 0, 0);
      acc = MFMA(al, bh, acc, 0, 0, 0);
      if (kt < 15) {
        bf16x8 bl = g_frag(wl + kt * 32);
        acc = MFMA(ah, bl, acc, 0, 0, 0);
      }
    }
    size_t ob = wb1 + (size_t)(r0 + rowB) * U_ + colG;
    for (int i = 0; i < 4; ++i) {
      float v = tanhf(acc[i]);
      unsigned short hi = f2b(v);
      h1h[ob + (size_t)i * U_] = hi;
      h1l[ob + (size_t)i * U_] = f2b(v - b2f(hi));
    }
  }

  // ---- h0'(t) = tanh(embW[tok(t)] + h0'(t-1)@Wh0 + b0) ----
  if (t < T_) {
    const float b0v = b0[colG];
    const size_t wbuf = (size_t)(t & 1) * HS;
    f32x4 aC, aD = {0.f, 0.f, 0.f, 0.f};
    for (int i = 0; i < 4; ++i) {
      int tk = tokens[(size_t)(r0 + rowB + i) * T_ + t];
      aC[i] = b0v + b2f(embW[(size_t)tk * U_ + colG]);
    }
    const unsigned short* wh = Wh0hT + (size_t)colG * U_ + kgrp;
    const unsigned short* wl = Wh0lT + (size_t)colG * U_ + kgrp;
#pragma unroll
    for (int kt = 0; kt < 16; ++kt) {
      bf16x8 bh = g_frag(wh + kt * 32);
      bf16x8 bl = g_frag(wl + kt * 32);
      aC = MFMA(h0h_r[kt], bh, aC, 0, 0, 0);
      aD = MFMA(h0l_r[kt], bh, aD, 0, 0, 0);
      aD = MFMA(h0h_r[kt], bl, aD, 0, 0, 0);
    }
    size_t ob = wbuf + (size_t)(r0 + rowB) * U_ + colG;
    for (int i = 0; i < 4; ++i) {
      float v = tanhf(aC[i] + aD[i]);
      unsigned short hi = f2b(v);
      h0h[ob + (size_t)i * U_] = hi;
      h0l[ob + (size_t)i * U_] = f2b(v - b2f(hi));
    }
  }
}

__global__ void rnn_final(const unsigned short* __restrict__ h1h,
                          const unsigned short* __restrict__ h1l,
                          const float* __restrict__ Wo,
                          const float* __restrict__ bo, float* __restrict__ out) {
  int lane = threadIdx.x & 63;
  int b = blockIdx.x * 4 + (threadIdx.x >> 6);
  us8 hh = *(const us8*)(h1h + (size_t)b * U_ + lane * 8);
  us8 hl = *(const us8*)(h1l + (size_t)b * U_ + lane * 8);
  const float4* wp = (const float4*)(Wo + lane * 8);
  float4 w0 = wp[0], w1 = wp[1];
  float s = (b2f(hh[0]) + b2f(hl[0])) * w0.x + (b2f(hh[1]) + b2f(hl[1])) * w0.y +
            (b2f(hh[2]) + b2f(hl[2])) * w0.z + (b2f(hh[3]) + b2f(hl[3])) * w0.w +
            (b2f(hh[4]) + b2f(hl[4])) * w1.x + (b2f(hh[5]) + b2f(hl[5])) * w1.y +
            (b2f(hh[6]) + b2f(hl[6])) * w1.z + (b2f(hh[7]) + b2f(hl[7])) * w1.w;
  for (int off = 32; off > 0; off >>= 1) s += __shfl_down(s, off, 64);
  if (lane == 0) out[b] = 1.0f / (1.0f + expf(-(s + bo[0])));
}

extern "C" void kernel_launch(void* const* d_in, const int* in_sizes, int n_in,
                              void* d_out, int out_size, void* d_ws, size_t ws_size,
                              hipStream_t stream) {
  const int* tokens = (const int*)d_in[0];
  const float* emb = (const float*)d_in[1];
  const float* Wx0 = (const float*)d_in[2];
  const float* Wh0 = (const float*)d_in[3];
  const float* b0 = (const float*)d_in[4];
  const float* Wx1 = (const float*)d_in[5];
  const float* Wh1 = (const float*)d_in[6];
  const float* b1 = (const float*)d_in[7];
  const float* Wo = (const float*)d_in[8];
  const float* bo = (const float*)d_in[9];
  unsigned char* ws = (unsigned char*)d_ws;
  float* out = (float*)d_out;

  hipLaunchKernelGGL(rnn_init, dim3(1024), dim3(256), 0, stream, ws);
  hipLaunchKernelGGL(wt_prep, dim3((U_ * U_ + 255) / 256), dim3(256), 0, stream,
                     Wh0, Wx1, Wh1, ws);
  hipLaunchKernelGGL(embw_gemm, dim3(V_ / 64, U_ / 64), dim3(256), 0, stream,
                     emb, Wx0, (unsigned short*)(ws + EMBW_OFF));
  // The hardware dispatcher is the group barrier: one kernel per merged
  // window (h1'(t-1) + h0'(t)), 129 sequential launches (graph-replayed).
  for (int t = 0; t <= T_; ++t) {
    hipLaunchKernelGGL(rnn_step, dim3(NC * NG), dim3(512), 0, stream, t,
                       tokens, b0, b1, ws);
  }
  // final h1'(127) lives in buffer 127&1 == 1
  hipLaunchKernelGGL(rnn_final, dim3(256), dim3(256), 0, stream,
                     (const unsigned short*)(ws + H1H_OFF) + (size_t)1 * B_ * U_,
                     (const unsigned short*)(ws + H1L_OFF) + (size_t)1 * B_ * U_,
                     Wo, bo, out);
}